// Round 8
// baseline (584.830 us; speedup 1.0000x reference)
//
#include <hip/hip_runtime.h>

#define PAD   4
#define DD    9
#define ND    81
#define CCH   256
#define HH_   128
#define WW_   224
#define TH    8
#define TW    32
#define NTILES 448               // 7 wtiles * 16 htiles * 4 batch
#define PLANE  (HH_*WW_)         // 28672
#define DEPTH 4                  // software-pipeline depth (channels in flight)

// cross-lane neighbor fetch on the VALU pipe (no DS traffic).
// In this kernel's lane map (lane = 8*hh + wq) the left/right window quads
// live in lane-1 / lane+1. DPP row_shr/row_shl don't cross 16-lane rows
// (bound_ctrl -> 0), but every affected lane has wq==0 or wq==7 and is
// overridden by the edge quad below.
__device__ __forceinline__ float dpp_from_left(float x) {
    int i = __builtin_bit_cast(int, x);
    i = __builtin_amdgcn_update_dpp(0, i, 0x111, 0xf, 0xf, true);  // row_shr:1
    return __builtin_bit_cast(float, i);
}
__device__ __forceinline__ float dpp_from_right(float x) {
    int i = __builtin_bit_cast(int, x);
    i = __builtin_amdgcn_update_dpp(0, i, 0x101, 0xf, 0xf, true);  // row_shl:1
    return __builtin_bit_cast(float, i);
}

__global__ __launch_bounds__(576)
void corr_kernel(const float* __restrict__ first,
                 const float* __restrict__ second,
                 const float* __restrict__ zws,    // >=256 B of zeros in d_ws
                 float* __restrict__ out)
{
    const int bx   = blockIdx.x;                 // 0..447
    // XCD-chunked bijective swizzle (448 % 8 == 0)
    const int tile = (bx & 7) * 56 + (bx >> 3);
    const int wt   = tile % 7;
    const int ht   = (tile / 7) % 16;
    const int b    = tile / 112;
    const int w0   = wt * TW, h0 = ht * TH;

    const int dy   = threadIdx.x >> 6;           // wave id = dy (0..8)
    const int lane = threadIdx.x & 63;
    const int wq   = lane & 7;                   // column quad
    const int hh   = lane >> 3;                  // row within tile

    const int h = h0 + hh;
    const int w = w0 + 4 * wq;
    const int srow  = h + dy - PAD;
    const bool valid = (srow >= 0) && (srow < HH_);
    const int srowc = valid ? srow : 0;          // clamped for address arith only

    const size_t plane = PLANE;
    const float* fbase = first  + (size_t)b * CCH * plane;
    const float* sbase = second + (size_t)b * CCH * plane;

    const float* fp = fbase + (size_t)h * WW_ + w;
    const float* sp = valid ? (sbase + (size_t)srowc * WW_ + w) : zws;
    const size_t sinc = valid ? plane : 0;

    const bool isL = (wq == 0), isR = (wq == 7);
    const int  ecol   = isL ? (w0 - PAD) : (w0 + TW);
    const bool evalid = valid && ((isL && w0 > 0) || (isR && (w0 + TW) < WW_));
    const float* ep = evalid ? (sbase + (size_t)srowc * WW_ + ecol) : zws;
    const size_t einc = evalid ? plane : 0;

    float acc[DD][4];
    #pragma unroll
    for (int dx = 0; dx < DD; ++dx) { acc[dx][0]=0.f; acc[dx][1]=0.f; acc[dx][2]=0.f; acc[dx][3]=0.f; }

    // ---------- 4-deep prefetch: 12 dwordx4 in flight per wave ----------
    float4 fb[DEPTH], mb[DEPTH], eb[DEPTH];
    #pragma unroll
    for (int j = 0; j < DEPTH; ++j) {
        fb[j] = *(const float4*)fp;  fp += plane;
        mb[j] = *(const float4*)sp;  sp += sinc;
        eb[j] = *(const float4*)ep;  ep += einc;
    }

    for (int c4 = 0; c4 < CCH; c4 += DEPTH) {
        const bool more = (c4 + DEPTH < CCH);    // wave-uniform
        #pragma unroll
        for (int j = 0; j < DEPTH; ++j) {        // all buffer idx compile-time
            const float4 f = fb[j], m = mb[j], e = eb[j];
            if (more) {                          // refill slot j (channel c4+DEPTH+j)
                fb[j] = *(const float4*)fp;  fp += plane;
                mb[j] = *(const float4*)sp;  sp += sinc;
                eb[j] = *(const float4*)ep;  ep += einc;
            }

            float a0 = dpp_from_left (m.x), a1 = dpp_from_left (m.y),
                  a2 = dpp_from_left (m.z), a3 = dpp_from_left (m.w);
            float c0 = dpp_from_right(m.x), c1 = dpp_from_right(m.y),
                  c2 = dpp_from_right(m.z), c3 = dpp_from_right(m.w);
            if (isL) { a0 = e.x; a1 = e.y; a2 = e.z; a3 = e.w; }
            if (isR) { c0 = e.x; c1 = e.y; c2 = e.z; c3 = e.w; }

            const float s[12] = { a0, a1, a2, a3,
                                  m.x, m.y, m.z, m.w,
                                  c0, c1, c2, c3 };
            const float fv[4] = { f.x, f.y, f.z, f.w };

            #pragma unroll
            for (int dx = 0; dx < DD; ++dx)
                #pragma unroll
                for (int px = 0; px < 4; ++px)
                    acc[dx][px] += fv[px] * s[dx + px];
        }

        // bound inter-wave drift so shared first/second lines stay L1-resident
        if ((c4 & 63) == 60 && c4 + DEPTH < CCH) __syncthreads();
    }

    const float inv = 1.0f / (float)CCH;
    #pragma unroll
    for (int dx = 0; dx < DD; ++dx) {
        const int d = dy * DD + dx;
        float4 o = make_float4(acc[dx][0]*inv, acc[dx][1]*inv,
                               acc[dx][2]*inv, acc[dx][3]*inv);
        *(float4*)&out[(((size_t)b * ND + d) * HH_ + h) * WW_ + w] = o;
    }
}

extern "C" void kernel_launch(void* const* d_in, const int* in_sizes, int n_in,
                              void* d_out, int out_size, void* d_ws, size_t ws_size,
                              hipStream_t stream) {
    const float* first  = (const float*)d_in[0];
    const float* second = (const float*)d_in[1];
    float* out = (float*)d_out;
    // 256-B zero pad for all out-of-bounds pointer redirection (branchless halo)
    hipMemsetAsync(d_ws, 0, 256, stream);
    dim3 grid(NTILES);        // 448 blocks, 9 waves each (one dy per wave)
    dim3 block(9 * 64);
    corr_kernel<<<grid, block, 0, stream>>>(first, second, (const float*)d_ws, out);
}